// Round 3
// baseline (7250.942 us; speedup 1.0000x reference)
//
#include <hip/hip_runtime.h>
#include <hip/hip_bf16.h>
#include <hip/hip_cooperative_groups.h>

namespace cg = cooperative_groups;

// Problem constants: inputs [T,B,D], state [B,H], W_xh [D,H], W_hh [H,H], b_h [H]
#define T_STEPS 256
#define B_SZ    64
#define D_SZ    1024
#define H_SZ    2048

// fp16 everywhere (2^-11 rounding vs bf16's 2^-9). Weights stored x256 so all
// entries are fp16-normal (W ~ U(0,0.01); 0.6% would be denormal unscaled);
// accumulator scaled by 1/256 in epilogue.
#define W_SCALE     256.0f
#define W_INV_SCALE 0.00390625f

typedef __attribute__((ext_vector_type(8))) _Float16 f16x8;  // 8 fp16 (4 VGPRs)
typedef __attribute__((ext_vector_type(4))) float    f32x4;  // MFMA 16x16 accumulator

// ---------------- conversion kernels ----------------

__global__ void cvt_f32_f16(const float* __restrict__ in,
                            _Float16* __restrict__ out, int n, float scale) {
    int i = blockIdx.x * blockDim.x + threadIdx.x;
    if (i < n) out[i] = (_Float16)(in[i] * scale);
}

// in[rows][cols] (fp32) -> out[cols][rows] (fp16, scaled). cols = 1<<log2cols.
__global__ void transpose_to_f16(const float* __restrict__ in,
                                 _Float16* __restrict__ out,
                                 int rows, int log2cols, float scale) {
    int i = blockIdx.x * blockDim.x + threadIdx.x;
    int cols = 1 << log2cols;
    if (i >= rows * cols) return;
    int r = i >> log2cols;
    int c = i & (cols - 1);
    out[c * rows + r] = (_Float16)(in[i] * scale);
}

// ---------------- phase 1: x_proj = inputs @ W_xh + b_h ----------------
// A [M,K] fp16 row-major, BT [N,K] fp16 (W_xh^T, x256), C [M,N] fp32.
// Block = 256 thr (4 waves, 2x2), block tile 128x128, wave tile 64x64 (4x4 MFMA 16x16x32).
__global__ __launch_bounds__(256) void gemm_xproj(
    const _Float16* __restrict__ A,
    const _Float16* __restrict__ BT,
    const float* __restrict__ bias,
    float* __restrict__ C,
    int M, int N, int K)
{
    int wave = threadIdx.x >> 6;
    int lane = threadIdx.x & 63;
    int q = lane >> 4;          // quad: k = q*8 + j for A/B fragments
    int r = lane & 15;          // row (A) / col (B) within 16
    int m0 = blockIdx.x * 128 + (wave >> 1) * 64;
    int n0 = blockIdx.y * 128 + (wave & 1) * 64;

    f32x4 acc[4][4] = {};
    for (int k = 0; k < K; k += 32) {
        int kk = k + q * 8;
        f16x8 a[4], b[4];
#pragma unroll
        for (int i = 0; i < 4; i++)
            a[i] = *(const f16x8*)(A + (size_t)(m0 + i * 16 + r) * K + kk);
#pragma unroll
        for (int j = 0; j < 4; j++)
            b[j] = *(const f16x8*)(BT + (size_t)(n0 + j * 16 + r) * K + kk);
#pragma unroll
        for (int i = 0; i < 4; i++)
#pragma unroll
            for (int j = 0; j < 4; j++)
                acc[i][j] = __builtin_amdgcn_mfma_f32_16x16x32_f16(a[i], b[j], acc[i][j], 0, 0, 0);
    }
#pragma unroll
    for (int i = 0; i < 4; i++)
#pragma unroll
        for (int j = 0; j < 4; j++)
#pragma unroll
            for (int reg = 0; reg < 4; reg++) {
                int row = m0 + i * 16 + q * 4 + reg;   // C/D: col=lane&15, row=(lane>>4)*4+reg
                int col = n0 + j * 16 + r;
                C[(size_t)row * N + col] = acc[i][j][reg] * W_INV_SCALE + bias[col];
            }
}

// ---------------- phase 2: persistent recurrence ----------------
// h_t = tanh(h_{t-1} @ W_hh + x_proj_t), 256 steps in ONE cooperative kernel.
// 128 blocks x 256 thr (4 waves). Block owns 16 output columns (n0 = blockIdx.x*16);
// its W_hh^T slice [16 cols][2048 k] lives in LDS, pre-swizzled into MFMA B-fragment
// order: wfrag[kb][lane] = 16B fragment for k-block kb (k = kb*32 + (lane>>4)*8),
// col = n0 + (lane&15). ds_read_b128 stride-1, conflict-free, broadcast across waves.
// Wave w computes rows [16w,16w+16) x block cols, full K=2048 -> no reduction.
__global__ __launch_bounds__(256, 1) void rnn_persist(
    _Float16* __restrict__ hb0,            // [B,H] fp16 ping (holds h_0 initial state)
    _Float16* __restrict__ hb1,            // [B,H] fp16 pong
    const _Float16* __restrict__ WT,       // [H,H] fp16 = W_hh^T x256
    float* __restrict__ out,               // [T,B,H] fp32: x_proj in, h out (in place)
    float* __restrict__ final_out)         // [B,H] fp32
{
    __shared__ f16x8 wfrag[4096];          // 64 kb x 64 lanes x 16B = 64 KB

    int tid = threadIdx.x;
    int n0 = blockIdx.x * 16;

    // one-time W staging (uncoalesced read, 64 KB, amortized over 256 steps)
    for (int idx = tid; idx < 4096; idx += 256) {
        int kb = idx >> 6, l = idx & 63;
        wfrag[idx] = *(const f16x8*)(WT + (size_t)(n0 + (l & 15)) * H_SZ
                                        + kb * 32 + (l >> 4) * 8);
    }
    __syncthreads();

    cg::grid_group grid = cg::this_grid();

    int wave = tid >> 6, lane = tid & 63;
    int q = lane >> 4, r = lane & 15;
    int row0 = wave * 16;                  // this wave's 16 batch rows
    int col = n0 + r;

    for (int t = 0; t < T_STEPS; t++) {
        const _Float16* hp = (t & 1) ? hb1 : hb0;
        _Float16*       hn = (t & 1) ? hb0 : hb1;
        float* out_t = out + (size_t)t * B_SZ * H_SZ;

        // prefetch x_proj for this lane's 4 outputs (overlaps MFMA loop)
        float xp[4];
#pragma unroll
        for (int reg = 0; reg < 4; reg++)
            xp[reg] = out_t[(size_t)(row0 + q * 4 + reg) * H_SZ + col];

        f32x4 acc = {};
        const _Float16* arow = hp + (size_t)(row0 + r) * H_SZ + q * 8;
#pragma unroll 4
        for (int kb = 0; kb < 64; kb++) {
            f16x8 a = *(const f16x8*)(arow + kb * 32);
            f16x8 b = wfrag[kb * 64 + lane];
            acc = __builtin_amdgcn_mfma_f32_16x16x32_f16(a, b, acc, 0, 0, 0);
        }

#pragma unroll
        for (int reg = 0; reg < 4; reg++) {
            size_t o = (size_t)(row0 + q * 4 + reg) * H_SZ + col;
            float v = tanhf(acc[reg] * W_INV_SCALE + xp[reg]);
            out_t[o] = v;
            hn[o] = (_Float16)v;
            if (t == T_STEPS - 1) final_out[o] = v;
        }
        grid.sync();   // h_t visible device-wide before step t+1
    }
}

// ---------------- launcher ----------------

extern "C" void kernel_launch(void* const* d_in, const int* in_sizes, int n_in,
                              void* d_out, int out_size, void* d_ws, size_t ws_size,
                              hipStream_t stream) {
    const float* inputs = (const float*)d_in[0];   // [T,B,D]
    const float* state  = (const float*)d_in[1];   // [B,H]
    const float* W_xh   = (const float*)d_in[2];   // [D,H]
    const float* W_hh   = (const float*)d_in[3];   // [H,H]
    const float* b_h    = (const float*)d_in[4];   // [H]
    float* out = (float*)d_out;

    // workspace layout (fp16 buffers)
    const size_t OFF_IN   = 0;                                     // T*B*D fp16
    const size_t OFF_WXT  = OFF_IN  + (size_t)T_STEPS*B_SZ*D_SZ*2; // [H,D] fp16
    const size_t OFF_WHT  = OFF_WXT + (size_t)H_SZ*D_SZ*2;         // [H,H] fp16
    const size_t OFF_H0   = OFF_WHT + (size_t)H_SZ*H_SZ*2;         // [B,H] fp16
    const size_t OFF_H1   = OFF_H0  + (size_t)B_SZ*H_SZ*2;
    const size_t NEED     = OFF_H1  + (size_t)B_SZ*H_SZ*2;
    if (ws_size < NEED) return;  // insufficient scratch

    char* ws = (char*)d_ws;
    _Float16* inputs_f16 = (_Float16*)(ws + OFF_IN);
    _Float16* WxT        = (_Float16*)(ws + OFF_WXT);
    _Float16* WhT        = (_Float16*)(ws + OFF_WHT);
    _Float16* hbuf0      = (_Float16*)(ws + OFF_H0);
    _Float16* hbuf1      = (_Float16*)(ws + OFF_H1);

    const int n_in_el = T_STEPS * B_SZ * D_SZ;   // 16,777,216
    cvt_f32_f16<<<(n_in_el + 255) / 256, 256, 0, stream>>>(inputs, inputs_f16, n_in_el, 1.0f);
    transpose_to_f16<<<(D_SZ * H_SZ + 255) / 256, 256, 0, stream>>>(W_xh, WxT, D_SZ, 11, W_SCALE);
    transpose_to_f16<<<(H_SZ * H_SZ + 255) / 256, 256, 0, stream>>>(W_hh, WhT, H_SZ, 11, W_SCALE);
    cvt_f32_f16<<<(B_SZ * H_SZ + 255) / 256, 256, 0, stream>>>(state, hbuf0, B_SZ * H_SZ, 1.0f);

    // phase 1: x_proj -> d_out[0 : T*B*H]
    dim3 g1((T_STEPS * B_SZ) / 128, H_SZ / 128);
    gemm_xproj<<<g1, 256, 0, stream>>>(inputs_f16, WxT, b_h, out,
                                       T_STEPS * B_SZ, H_SZ, D_SZ);

    // phase 2: one cooperative dispatch, 256 steps with grid-wide sync
    float* final_out = out + (size_t)T_STEPS * B_SZ * H_SZ;
    void* args[] = { (void*)&hbuf0, (void*)&hbuf1, (void*)&WhT,
                     (void*)&out, (void*)&final_out };
    hipLaunchCooperativeKernel((void*)rnn_persist, dim3(128), dim3(256),
                               args, 0, stream);
}

// Round 4
// 4587.080 us; speedup vs baseline: 1.5807x; 1.5807x over previous
//
#include <hip/hip_runtime.h>
#include <hip/hip_bf16.h>

// Problem constants: inputs [T,B,D], state [B,H], W_xh [D,H], W_hh [H,H], b_h [H]
#define T_STEPS 256
#define B_SZ    64
#define D_SZ    1024
#define H_SZ    2048
#define NBLK    64      // persistent blocks (<= 256 CUs, coop-launched)

// fp16 everywhere (2^-11 rounding). Weights stored x256 so all entries are
// fp16-normal (W ~ U(0,0.01)); accumulator scaled by 1/256 in epilogue.
#define W_SCALE     256.0f
#define W_INV_SCALE 0.00390625f

typedef __attribute__((ext_vector_type(8))) _Float16 f16x8;  // 8 fp16 (4 VGPRs)
typedef __attribute__((ext_vector_type(4))) float    f32x4;  // MFMA 16x16 accumulator

// ---------------- conversion kernels ----------------

__global__ void cvt_f32_f16(const float* __restrict__ in,
                            _Float16* __restrict__ out, int n, float scale) {
    int i = blockIdx.x * blockDim.x + threadIdx.x;
    if (i < n) out[i] = (_Float16)(in[i] * scale);
}

// in[rows][cols] (fp32) -> out[cols][rows] (fp16, scaled). cols = 1<<log2cols.
__global__ void transpose_to_f16(const float* __restrict__ in,
                                 _Float16* __restrict__ out,
                                 int rows, int log2cols, float scale) {
    int i = blockIdx.x * blockDim.x + threadIdx.x;
    int cols = 1 << log2cols;
    if (i >= rows * cols) return;
    int r = i >> log2cols;
    int c = i & (cols - 1);
    out[c * rows + r] = (_Float16)(in[i] * scale);
}

__global__ void init_ctr(unsigned int* ctr) { *ctr = 0u; }

// ---------------- phase 1: x_proj = inputs @ W_xh + b_h ----------------
// A [M,K] fp16 row-major, BT [N,K] fp16 (W_xh^T, x256), C [M,N] fp32.
__global__ __launch_bounds__(256) void gemm_xproj(
    const _Float16* __restrict__ A,
    const _Float16* __restrict__ BT,
    const float* __restrict__ bias,
    float* __restrict__ C,
    int M, int N, int K)
{
    int wave = threadIdx.x >> 6;
    int lane = threadIdx.x & 63;
    int q = lane >> 4;          // quad: k = q*8 + j for A/B fragments
    int r = lane & 15;          // row (A) / col (B) within 16
    int m0 = blockIdx.x * 128 + (wave >> 1) * 64;
    int n0 = blockIdx.y * 128 + (wave & 1) * 64;

    f32x4 acc[4][4] = {};
    for (int k = 0; k < K; k += 32) {
        int kk = k + q * 8;
        f16x8 a[4], b[4];
#pragma unroll
        for (int i = 0; i < 4; i++)
            a[i] = *(const f16x8*)(A + (size_t)(m0 + i * 16 + r) * K + kk);
#pragma unroll
        for (int j = 0; j < 4; j++)
            b[j] = *(const f16x8*)(BT + (size_t)(n0 + j * 16 + r) * K + kk);
#pragma unroll
        for (int i = 0; i < 4; i++)
#pragma unroll
            for (int j = 0; j < 4; j++)
                acc[i][j] = __builtin_amdgcn_mfma_f32_16x16x32_f16(a[i], b[j], acc[i][j], 0, 0, 0);
    }
#pragma unroll
    for (int i = 0; i < 4; i++)
#pragma unroll
        for (int j = 0; j < 4; j++)
#pragma unroll
            for (int reg = 0; reg < 4; reg++) {
                int row = m0 + i * 16 + q * 4 + reg;   // C/D: col=lane&15, row=(lane>>4)*4+reg
                int col = n0 + j * 16 + r;
                C[(size_t)row * N + col] = acc[i][j][reg] * W_INV_SCALE + bias[col];
            }
}

// ---------------- phase 2: persistent recurrence, hand-rolled barrier ----------------
// 64 blocks x 256 thr (4 waves). Block owns 32 output columns; W_hh^T slice
// [32 cols][2048 k] pre-swizzled into LDS in MFMA B-fragment order (128 KB).
// Wave w computes rows [16w,16w+16) x 32 cols, full K=2048 (no cross-wave reduce).
// Cross-block coherence: h_next written via agent-scope 8B atomic stores
// (write-through to device-coherent LLC); readers do one agent acquire fence
// (L1/L2 invalidate, no writeback) per step, then plain dwordx4 loads.
// Barrier: monotonic agent-scope counter, single-thread relaxed spin.
__global__ __launch_bounds__(256, 1) void rnn_persist(
    _Float16* __restrict__ hb0,            // [B,H] fp16 ping (holds h_0)
    _Float16* __restrict__ hb1,            // [B,H] fp16 pong
    const _Float16* __restrict__ WT,       // [H,H] fp16 = W_hh^T x256
    float* __restrict__ out,               // [T,B,H] fp32: x_proj in, h out (in place)
    float* __restrict__ final_out,         // [B,H] fp32
    unsigned int* __restrict__ ctr)        // barrier counter (pre-zeroed)
{
    __shared__ f16x8 wfrag[8192];                     // 64 kb x 2 j x 64 lanes = 128 KB
    __shared__ __align__(16) _Float16 hsl[64 * 32];   // 4 KB h-slice repack

    int tid = threadIdx.x;
    int n0 = blockIdx.x * 32;

    // one-time W staging into fragment order: idx = (kb*2+j)*64 + l
    for (int idx = tid; idx < 8192; idx += 256) {
        int kb = idx >> 7, j = (idx >> 6) & 1, l = idx & 63;
        wfrag[idx] = *(const f16x8*)(WT + (size_t)(n0 + j * 16 + (l & 15)) * H_SZ
                                        + kb * 32 + (l >> 4) * 8);
    }
    __syncthreads();

    int wave = tid >> 6, lane = tid & 63;
    int q = lane >> 4, r = lane & 15;
    int row0 = wave * 16;                  // this wave's 16 batch rows

    for (int t = 0; t < T_STEPS; t++) {
        const _Float16* hp = (t & 1) ? hb1 : hb0;
        _Float16*       hn = (t & 1) ? hb0 : hb1;
        float* out_t = out + (size_t)t * B_SZ * H_SZ;

        // x_proj prefetch (independent of h; overlaps MFMA loop)
        float xp[2][4];
#pragma unroll
        for (int j = 0; j < 2; j++)
#pragma unroll
            for (int reg = 0; reg < 4; reg++)
                xp[j][reg] = out_t[(size_t)(row0 + q * 4 + reg) * H_SZ + n0 + j * 16 + r];

        f32x4 acc[2] = {};
        const _Float16* arow = hp + (size_t)(row0 + r) * H_SZ + q * 8;
#pragma unroll 8
        for (int kb = 0; kb < 64; kb++) {
            f16x8 a = *(const f16x8*)(arow + kb * 32);
            acc[0] = __builtin_amdgcn_mfma_f32_16x16x32_f16(a, wfrag[kb * 128 + lane],      acc[0], 0, 0, 0);
            acc[1] = __builtin_amdgcn_mfma_f32_16x16x32_f16(a, wfrag[kb * 128 + 64 + lane], acc[1], 0, 0, 0);
        }

        // epilogue: tanh, fp32 out, fp16 h into LDS for coalesced coherent store
#pragma unroll
        for (int j = 0; j < 2; j++)
#pragma unroll
            for (int reg = 0; reg < 4; reg++) {
                int row = row0 + q * 4 + reg;
                int cl  = j * 16 + r;
                float v = tanhf(acc[j][reg] * W_INV_SCALE + xp[j][reg]);
                out_t[(size_t)row * H_SZ + n0 + cl] = v;
                hsl[row * 32 + cl] = (_Float16)v;
                if (t == T_STEPS - 1) final_out[(size_t)row * H_SZ + n0 + cl] = v;
            }
        __syncthreads();   // hsl complete (also drains vmcnt)

        // coherent h store: 64 rows x 32 cols = 512 x 8B, coalesced
        for (int idx = tid; idx < 512; idx += 256) {
            int row = idx >> 3, part = idx & 7;
            unsigned long long vv = ((const unsigned long long*)(hsl + row * 32))[part];
            __hip_atomic_store((unsigned long long*)(hn + (size_t)row * H_SZ + n0) + part,
                               vv, __ATOMIC_RELAXED, __HIP_MEMORY_SCOPE_AGENT);
        }
        if (t == T_STEPS - 1) break;

        __syncthreads();   // drain atomic stores (vmcnt 0) before arriving
        if (tid == 0) {
            __hip_atomic_fetch_add(ctr, 1u, __ATOMIC_RELEASE, __HIP_MEMORY_SCOPE_AGENT);
            unsigned int target = (unsigned int)(t + 1) * NBLK;
            while (__hip_atomic_load(ctr, __ATOMIC_RELAXED, __HIP_MEMORY_SCOPE_AGENT) < target)
                __builtin_amdgcn_s_sleep(2);
        }
        __syncthreads();
        __builtin_amdgcn_fence(__ATOMIC_ACQUIRE, "agent");  // inv L1/L2; next h reads hit LLC
    }
}

// ---------------- launcher ----------------

extern "C" void kernel_launch(void* const* d_in, const int* in_sizes, int n_in,
                              void* d_out, int out_size, void* d_ws, size_t ws_size,
                              hipStream_t stream) {
    const float* inputs = (const float*)d_in[0];   // [T,B,D]
    const float* state  = (const float*)d_in[1];   // [B,H]
    const float* W_xh   = (const float*)d_in[2];   // [D,H]
    const float* W_hh   = (const float*)d_in[3];   // [H,H]
    const float* b_h    = (const float*)d_in[4];   // [H]
    float* out = (float*)d_out;

    // workspace layout (fp16 buffers + barrier counter)
    const size_t OFF_IN   = 0;                                     // T*B*D fp16
    const size_t OFF_WXT  = OFF_IN  + (size_t)T_STEPS*B_SZ*D_SZ*2; // [H,D] fp16
    const size_t OFF_WHT  = OFF_WXT + (size_t)H_SZ*D_SZ*2;         // [H,H] fp16
    const size_t OFF_H0   = OFF_WHT + (size_t)H_SZ*H_SZ*2;         // [B,H] fp16
    const size_t OFF_H1   = OFF_H0  + (size_t)B_SZ*H_SZ*2;
    const size_t OFF_CTR  = OFF_H1  + (size_t)B_SZ*H_SZ*2;
    const size_t NEED     = OFF_CTR + 64;
    if (ws_size < NEED) return;  // insufficient scratch

    char* ws = (char*)d_ws;
    _Float16* inputs_f16 = (_Float16*)(ws + OFF_IN);
    _Float16* WxT        = (_Float16*)(ws + OFF_WXT);
    _Float16* WhT        = (_Float16*)(ws + OFF_WHT);
    _Float16* hbuf0      = (_Float16*)(ws + OFF_H0);
    _Float16* hbuf1      = (_Float16*)(ws + OFF_H1);
    unsigned int* ctr    = (unsigned int*)(ws + OFF_CTR);

    const int n_in_el = T_STEPS * B_SZ * D_SZ;   // 16,777,216
    cvt_f32_f16<<<(n_in_el + 255) / 256, 256, 0, stream>>>(inputs, inputs_f16, n_in_el, 1.0f);
    transpose_to_f16<<<(D_SZ * H_SZ + 255) / 256, 256, 0, stream>>>(W_xh, WxT, D_SZ, 11, W_SCALE);
    transpose_to_f16<<<(H_SZ * H_SZ + 255) / 256, 256, 0, stream>>>(W_hh, WhT, H_SZ, 11, W_SCALE);
    cvt_f32_f16<<<(B_SZ * H_SZ + 255) / 256, 256, 0, stream>>>(state, hbuf0, B_SZ * H_SZ, 1.0f);
    init_ctr<<<1, 1, 0, stream>>>(ctr);   // harness re-poisons ws every launch

    // phase 1: x_proj -> d_out[0 : T*B*H]
    dim3 g1((T_STEPS * B_SZ) / 128, H_SZ / 128);
    gemm_xproj<<<g1, 256, 0, stream>>>(inputs_f16, WxT, b_h, out,
                                       T_STEPS * B_SZ, H_SZ, D_SZ);

    // phase 2: one cooperative dispatch (co-residency guarantee), own barrier
    float* final_out = out + (size_t)T_STEPS * B_SZ * H_SZ;
    void* args[] = { (void*)&hbuf0, (void*)&hbuf1, (void*)&WhT,
                     (void*)&out, (void*)&final_out, (void*)&ctr };
    hipLaunchCooperativeKernel((void*)rnn_persist, dim3(NBLK), dim3(256),
                               args, 0, stream);
}